// Round 1
// baseline (691.477 us; speedup 1.0000x reference)
//
#include <hip/hip_runtime.h>
#include <hip/hip_bf16.h>

typedef __attribute__((ext_vector_type(8))) short short8;
typedef __attribute__((ext_vector_type(4))) float float4v;

__device__ __forceinline__ unsigned short f2bf(float f) {
    unsigned int u = __float_as_uint(f);
    u += 0x7fffu + ((u >> 16) & 1u);   // round-to-nearest-even
    return (unsigned short)(u >> 16);
}

// ---------------- K1: per-block element histogram (no atomics) ----------------
__global__ void count_kernel(const int* __restrict__ elem, int n, int* __restrict__ bc) {
    const int t = threadIdx.x, b = blockIdx.x;
    const int base = b * 1024;
    int c[4] = {0, 0, 0, 0};
    #pragma unroll
    for (int i = 0; i < 4; ++i) {
        const int a = base + i * 256 + t;
        if (a < n) c[elem[a]]++;
    }
    int p0 = c[0] | (c[1] << 16);
    int p1 = c[2] | (c[3] << 16);
    #pragma unroll
    for (int off = 1; off < 64; off <<= 1) { p0 += __shfl_xor(p0, off); p1 += __shfl_xor(p1, off); }
    __shared__ int wsum[4][4];
    const int w = t >> 6, lane = t & 63;
    if (lane == 0) {
        wsum[w][0] = p0 & 0xffff; wsum[w][1] = p0 >> 16;
        wsum[w][2] = p1 & 0xffff; wsum[w][3] = p1 >> 16;
    }
    __syncthreads();
    if (t < 4) {
        int s = 0;
        #pragma unroll
        for (int ww = 0; ww < 4; ++ww) s += wsum[ww][t];
        bc[b * 4 + t] = s;
    }
}

// ---------------- K2: scan per-block counts -> global bases (1 block) ----------------
__global__ void scan_kernel(int* __restrict__ bc, int* __restrict__ offs, int nb) {
    const int t = threadIdx.x, w = t >> 6, lane = t & 63;   // wave w handles element w
    int vals[16];
    int s = 0;
    #pragma unroll
    for (int j = 0; j < 16; ++j) {
        const int i = lane * 16 + j;
        const int v = (i < nb) ? bc[i * 4 + w] : 0;
        vals[j] = s; s += v;
    }
    int incl = s;
    #pragma unroll
    for (int off = 1; off < 64; off <<= 1) {
        const int v = __shfl_up(incl, off);
        if (lane >= off) incl += v;
    }
    const int excl = incl - s;
    __shared__ int tot[4];
    __shared__ int eoff[4];
    if (lane == 63) tot[w] = incl;
    __syncthreads();
    if (t == 0) {
        int a = 0;
        for (int e = 0; e < 4; ++e) { eoff[e] = a; offs[e] = a; a += tot[e]; }
        offs[4] = a;
    }
    __syncthreads();
    const int myoff = eoff[w] + excl;
    #pragma unroll
    for (int j = 0; j < 16; ++j) {
        const int i = lane * 16 + j;
        if (i < nb) bc[i * 4 + w] = myoff + vals[j];
    }
}

// ---------------- K3: stable-ish scatter of atom indices into buckets (no atomics) ----------------
__global__ void scatter_kernel(const int* __restrict__ elem, int n,
                               const int* __restrict__ bc, int* __restrict__ idx_sorted) {
    const int t = threadIdx.x, b = blockIdx.x;
    const int w = t >> 6, lane = t & 63;
    const int base = b * 1024;
    int ev[4];
    #pragma unroll
    for (int i = 0; i < 4; ++i) {
        const int a = base + i * 256 + t;
        ev[i] = (a < n) ? elem[a] : -1;
    }
    __shared__ int tbl[4][4][4];   // [iter][wave][elem] counts -> exclusive offsets
    __shared__ int sbase[4];
    #pragma unroll
    for (int i = 0; i < 4; ++i) {
        #pragma unroll
        for (int el = 0; el < 4; ++el) {
            const unsigned long long m = __ballot(ev[i] == el);
            if (lane == 0) tbl[i][w][el] = (int)__popcll(m);
        }
    }
    if (t < 4) sbase[t] = bc[b * 4 + t];
    __syncthreads();
    if (t < 4) {
        int s = 0;
        for (int i = 0; i < 4; ++i)
            for (int w2 = 0; w2 < 4; ++w2) { const int v = tbl[i][w2][t]; tbl[i][w2][t] = s; s += v; }
    }
    __syncthreads();
    #pragma unroll
    for (int i = 0; i < 4; ++i) {
        unsigned long long m[4];
        #pragma unroll
        for (int el = 0; el < 4; ++el) m[el] = __ballot(ev[i] == el);
        const int a = base + i * 256 + t;
        if (a < n) {
            const int el = ev[i];
            const int rank = (int)__popcll(m[el] & ((1ull << lane) - 1ull));
            idx_sorted[sbase[el] + tbl[i][w][el] + rank] = a;
        }
    }
}

// ---------------- K4: W1 [e][k][n] fp32 -> W1T [e][n][k] bf16 ----------------
__global__ void w1t_kernel(const float* __restrict__ W1, unsigned short* __restrict__ W1T) {
    const int b = blockIdx.x;            // 512 blocks = e*128 + n
    const int e = b >> 7, nn = b & 127;
    const int k = threadIdx.x;           // 128 threads
    const float v = W1[((size_t)(e * 128 + k)) * 128 + nn];
    W1T[((size_t)(e * 128 + nn)) * 128 + k] = f2bf(v);
}

// ---------------- K5: gather-GEMM + fused layer-2 epilogue ----------------
__global__ __launch_bounds__(256, 2)
void expert_mlp_kernel(const float* __restrict__ desc,
                       const unsigned short* __restrict__ W1T,
                       const float* __restrict__ b1,
                       const float* __restrict__ W2,
                       const float* __restrict__ b2,
                       const int* __restrict__ idx_sorted,
                       const int* __restrict__ offs,
                       float* __restrict__ out) {
    __shared__ unsigned short As[128 * 128];   // desc tile, bf16, XOR-swizzled (32 KB)
    __shared__ unsigned short Bs[128 * 128];   // W1T[e],   bf16, XOR-swizzled (32 KB)

    const int bx = blockIdx.x;
    const int e = bx & 3;
    const int tile = bx >> 2;
    const int base = offs[e];
    const int cnt = offs[e + 1] - base;
    const int m0 = tile * 128;
    if (m0 >= cnt) return;
    const int t = threadIdx.x;

    // stage Bs: W1T[e] rows n contiguous in k; swizzle chunk c(16B) -> c ^ (n&7)
    {
        const uint4* src = (const uint4*)(W1T + (size_t)e * 16384);
        const int c = t & 15, nrow = t >> 4;
        #pragma unroll
        for (int p = 0; p < 8; ++p) {
            const int nn = nrow + p * 16;
            const uint4 v = src[nn * 16 + c];
            const int pc = c ^ (nn & 7);
            *(uint4*)(&Bs[nn * 128 + pc * 8]) = v;
        }
    }
    // stage As: gather desc rows via idx_sorted, fp32 -> bf16
    {
        const int c = t & 31, rr = t >> 5;
        #pragma unroll
        for (int p = 0; p < 16; ++p) {
            const int r = p * 8 + rr;
            const int gm = m0 + r;
            const int gi = idx_sorted[base + ((gm < cnt) ? gm : 0)];
            const float4 v = *(const float4*)(desc + (size_t)gi * 128 + c * 4);
            ushort4 pk;
            pk.x = f2bf(v.x); pk.y = f2bf(v.y); pk.z = f2bf(v.z); pk.w = f2bf(v.w);
            const int pc = (c >> 1) ^ (r & 7);
            *(ushort4*)(&As[r * 128 + pc * 8 + (c & 1) * 4]) = pk;
        }
    }
    __syncthreads();

    const int lane = t & 63;
    const int wv = t >> 6;
    const int quad = lane >> 4;
    const int l16 = lane & 15;
    const int mbase = wv * 32;          // wave handles 32 atom-rows
    const int r7 = l16 & 7;

    float4v acc[2][8] = {};
    #pragma unroll
    for (int ks = 0; ks < 4; ++ks) {
        const int pco = ((ks * 4 + quad) ^ r7) * 8;
        const short8 a0 = *(const short8*)(&As[(mbase + l16) * 128 + pco]);
        const short8 a1 = *(const short8*)(&As[(mbase + 16 + l16) * 128 + pco]);
        #pragma unroll
        for (int nt = 0; nt < 8; ++nt) {
            const short8 bf = *(const short8*)(&Bs[(nt * 16 + l16) * 128 + pco]);
            acc[0][nt] = __builtin_amdgcn_mfma_f32_16x16x32_bf16(a0, bf, acc[0][nt], 0, 0, 0);
            acc[1][nt] = __builtin_amdgcn_mfma_f32_16x16x32_bf16(a1, bf, acc[1][nt], 0, 0, 0);
        }
    }

    // fused layer 2 in fp32: y[m] = sum_n relu(H[m][n] + b1[n]) * W2[n] + b2
    float b1v[8], w2v[8];
    #pragma unroll
    for (int nt = 0; nt < 8; ++nt) {
        b1v[nt] = b1[e * 128 + nt * 16 + l16];
        w2v[nt] = W2[e * 128 + nt * 16 + l16];
    }
    const float b2e = b2[e];
    #pragma unroll
    for (int mt = 0; mt < 2; ++mt) {
        float y[4] = {0.f, 0.f, 0.f, 0.f};
        #pragma unroll
        for (int nt = 0; nt < 8; ++nt) {
            const float4v v = acc[mt][nt];
            #pragma unroll
            for (int r = 0; r < 4; ++r)
                y[r] += fmaxf(v[r] + b1v[nt], 0.f) * w2v[nt];
        }
        #pragma unroll
        for (int off = 1; off < 16; off <<= 1) {
            #pragma unroll
            for (int r = 0; r < 4; ++r) y[r] += __shfl_xor(y[r], off, 16);
        }
        if (l16 == 0) {
            #pragma unroll
            for (int r = 0; r < 4; ++r) {
                const int m = mbase + mt * 16 + quad * 4 + r;   // C: row = quad*4 + reg
                const int gm = m0 + m;
                if (gm < cnt) out[idx_sorted[base + gm]] = y[r] + b2e;
            }
        }
    }
}

extern "C" void kernel_launch(void* const* d_in, const int* in_sizes, int n_in,
                              void* d_out, int out_size, void* d_ws, size_t ws_size,
                              hipStream_t stream) {
    const int*   elem = (const int*)d_in[0];
    const float* desc = (const float*)d_in[1];
    const float* W1   = (const float*)d_in[2];
    const float* b1   = (const float*)d_in[3];
    const float* W2   = (const float*)d_in[4];
    const float* b2   = (const float*)d_in[5];
    float* out = (float*)d_out;
    const int n = in_sizes[0];

    char* ws = (char*)d_ws;
    int* bc         = (int*)ws;                         // [nb][4] counts -> global bases
    int* offs       = (int*)(ws + 16128);               // [5] bucket offsets
    int* idx_sorted = (int*)(ws + 16384);               // [n]
    unsigned short* W1T = (unsigned short*)(ws + 16384 + (size_t)n * 4); // [4][128][128] bf16

    const int nb = (n + 1023) / 1024;
    count_kernel  <<<nb, 256, 0, stream>>>(elem, n, bc);
    scan_kernel   <<<1, 256, 0, stream>>>(bc, offs, nb);
    scatter_kernel<<<nb, 256, 0, stream>>>(elem, n, bc, idx_sorted);
    w1t_kernel    <<<512, 128, 0, stream>>>(W1, W1T);

    const int tiles = (n + 127) / 128;
    expert_mlp_kernel<<<tiles * 4, 256, 0, stream>>>(desc, W1T, b1, W2, b2, idx_sorted, offs, out);
}